// Round 15
// baseline (420.125 us; speedup 1.0000x reference)
//
#include <hip/hip_runtime.h>
#include <stdint.h>

typedef __attribute__((ext_vector_type(8))) short short8;
typedef __attribute__((ext_vector_type(4))) float f32x4;
typedef unsigned short ushort_t;

#define T_STEPS 10
#define WPACK_BYTES (2048*1024)                 // 2048 chunks x 1 KiB
#define VBUF_OFF  WPACK_BYTES
#define HBF_OFF   (WPACK_BYTES + 8192)
#define H_ELEMS   (8192ull*T_STEPS*512)
#define HBF_BYTES (H_ELEMS*2)

typedef const __attribute__((address_space(1))) void gas_void;
typedef __attribute__((address_space(3))) void las_void;

__device__ __forceinline__ void gld_lds16(const void* g, void* l){
  __builtin_amdgcn_global_load_lds((gas_void*)g, (las_void*)l, 16, 0, 0);
}

__device__ __forceinline__ unsigned int pk2(float x, float y){
  unsigned int bx = __float_as_uint(x), by = __float_as_uint(y);
  bx = (bx + 0x7FFFu + ((bx>>16)&1u)) >> 16;     // RNE fp32->bf16
  by = (by + 0x7FFFu + ((by>>16)&1u)) >> 16;
  return bx | (by<<16);
}
__device__ __forceinline__ float sigf(float x){ return 1.f/(1.f + __expf(-x)); }
__device__ __forceinline__ float tanh_(float x){
  x = fminf(fmaxf(x, -15.f), 15.f);
  float e = __expf(2.f*x);
  return (e - 1.f)/(e + 1.f);
}

// ---- K0a: pack W_hh [2048][512] fp32 -> bf16 B-fragment chunks -------------
// chunk = ((jb4*4 + jt4)*4 + g)*16 + kc (jb4 0..7 block of 64 j, jt4 0..3)
// in-chunk lane = khi*16 + jl ; j = jb4*64 + jt4*16 + jl
__global__ __launch_bounds__(256) void k_pack(const float* __restrict__ Whh,
                                              ushort_t* __restrict__ wp){
  int id  = blockIdx.x*256 + threadIdx.x;
  int row = id >> 6;
  int ko  = (id & 63) * 8;
  const float* p = Whh + row*512 + ko;
  float4 a = *(const float4*)p, b = *(const float4*)(p+4);
  uint4 v;
  v.x = pk2(a.x,a.y); v.y = pk2(a.z,a.w);
  v.z = pk2(b.x,b.y); v.w = pk2(b.z,b.w);
  int g = row >> 9, j = row & 511;
  int jb = j >> 6, jt = (j >> 4) & 3, jl = j & 15;
  int kc = ko >> 5, khi = (ko >> 3) & 3, lane = khi*16 + jl;
  int chunk = ((jb*4 + jt)*4 + g)*16 + kc;
  *(uint4*)(wp + chunk*512 + lane*8) = v;
}

// ---- K0b -------------------------------------------------------------------
__global__ __launch_bounds__(256) void k_v(const float* __restrict__ fc1w,
                                           const float* __restrict__ fc1b,
                                           const float* __restrict__ fc2w,
                                           const float* __restrict__ fc2b,
                                           float* __restrict__ vout,
                                           float* __restrict__ bias0){
  __shared__ float red[4][64];
  int tid = threadIdx.x;
  if (blockIdx.x < 16){
    int j  = blockIdx.x*64 + (tid & 63);
    int hc = tid >> 6;
    float s = 0.f;
    for (int hh = hc*128; hh < hc*128 + 128; ++hh)
      s += fc2w[hh] * fc1w[hh*1024 + j];
    red[hc][tid & 63] = s;
    __syncthreads();
    if (tid < 64)
      vout[blockIdx.x*64 + tid] = red[0][tid]+red[1][tid]+red[2][tid]+red[3][tid];
  } else {
    if (tid < 64){
      float s = 0.f;
      for (int i = 0; i < 8; ++i){ int hh = i*64 + tid; s += fc2w[hh]*fc1b[hh]; }
      for (int m = 32; m; m >>= 1) s += __shfl_xor(s, m);
      if (tid == 0) *bias0 = s + fc2b[0];
    }
  }
}

// ---- K2 --------------------------------------------------------------------
__global__ __launch_bounds__(512) void k_init(const float* __restrict__ h,
                                              const float* __restrict__ v,
                                              const float* __restrict__ bias0,
                                              float* __restrict__ out){
  int w = threadIdx.x >> 6, lane = threadIdx.x & 63;
  float b0v = *bias0;
  const float* v2 = v + 512;
  for (int r = 0; r < 8; ++r){
    int b = blockIdx.x*64 + w*8 + r;
    const float* hp = h + ((size_t)b*T_STEPS + 9)*512 + lane*8;
    float4 x0 = *(const float4*)hp, x1 = *(const float4*)(hp+4);
    const float* vp = v2 + lane*8;
    float4 w0 = *(const float4*)vp, w1 = *(const float4*)(vp+4);
    float s = x0.x*w0.x + x0.y*w0.y + x0.z*w0.z + x0.w*w0.w
            + x1.x*w1.x + x1.y*w1.y + x1.z*w1.z + x1.w*w1.w;
    for (int m = 32; m; m >>= 1) s += __shfl_xor(s, m);
    if (lane == 0) out[b] = s + b0v;
  }
}

// ---- K0c: h fp32 -> bf16, quad-major per-slice, BT=256 tiles ---------------
// hbf granule(16B) = ((tile*10 + t)*16 + kc)*1024 + kq*256 + row
// (tile = b>>8, row = b&255, k = kc*32 + kq*8 + e)
// grid = 32 tiles x 10 t x 2 row-halves = 640 blocks x 256 threads.
__global__ __launch_bounds__(256) void k_prep(const float* __restrict__ h,
                                              ushort_t* __restrict__ hbf){
  __shared__ __align__(16) ushort_t buf[8192*8];     // 128 KiB
  int bid = blockIdx.x;
  int T = bid / 20, rem = bid % 20, t = rem >> 1, half = rem & 1;
  int tid = threadIdx.x;
  int row128 = tid >> 1, khalf = tid & 1;
  const float* src = h + ((size_t)(T*256 + half*128 + row128)*T_STEPS + t)*512
                   + khalf*256;
#pragma unroll
  for (int g = 0; g < 32; ++g){
    int k0 = khalf*256 + g*8;
    float4 a = *(const float4*)(src + g*8);
    float4 b = *(const float4*)(src + g*8 + 4);
    uint4 pk;
    pk.x = pk2(a.x,a.y); pk.y = pk2(a.z,a.w);
    pk.z = pk2(b.x,b.y); pk.w = pk2(b.z,b.w);
    int kc = k0 >> 5, kq = (k0 >> 3) & 3;
    *(uint4*)&buf[(size_t)(kc*512 + kq*128 + row128)*8] = pk;
  }
  __syncthreads();
  size_t sb = ((size_t)(T*T_STEPS + t)*16)*1024;
#pragma unroll
  for (int i = 0; i < 32; ++i){
    int gr = tid + i*256;                        // buf granule (kc,kq,r)
    int kc = gr >> 9, kq = (gr >> 7) & 3, r = gr & 127;
    size_t dg = sb + (size_t)kc*1024 + kq*256 + half*128 + r;
    *(uint4*)(hbf + dg*8) = *(const uint4*)&buf[gr*8];
  }
}

// ============================================================================
// K1 (PREP): W-in-LDS-once + barrier-free A pipeline.
// 512 blocks (32 tiles x 16 jb) x 256 thr (4 waves), 1 block/CU (138 KB LDS).
// Wave tile: m4 (64 rows) x n2 (32 j) x 3 gates = 24 MFMA/slice.
// W{i,f,g} (96 KB) loaded to LDS ONCE; A: wave-private LDS dbuf (zero barriers
// in main loop); named register sets, 2-unrolled loop (static indexing).
// ============================================================================
struct RegSet { short8 af[4]; short8 wf[3][2]; };

__global__ __launch_bounds__(256)
__attribute__((amdgpu_waves_per_eu(1, 1)))
void k_main_p(const ushort_t* __restrict__ hbf, const float* __restrict__ y,
              const float* __restrict__ Wih, const float* __restrict__ bih,
              const float* __restrict__ bhh,
              const ushort_t* __restrict__ wpack, const float* __restrict__ v1,
              float* __restrict__ out)
{
  __shared__ __align__(16) ushort_t Wlds[96*512];    // 96 KiB, read-only
  __shared__ __align__(16) ushort_t Ab[2][4][2048];  // 32 KiB, wave-private
  __shared__ float ys[256*T_STEPS];                  // 10 KiB

  int tid = threadIdx.x;
  int w = tid >> 6, lane = tid & 63, lhi = lane >> 4, llo = lane & 15;
  int bid = blockIdx.x;
  int xcd = bid & 7, q = bid >> 3;
  int jb  = q & 15;                                  // j-block of 32
  int tile = xcd*2 + ((q >> 4) & 1) + ((q >> 5) << 4);
  int b0 = tile * 256;

  float bias2[4][2], wihv[4][2], v1v[2];
#pragma unroll
  for (int g = 0; g < 4; ++g)
#pragma unroll
    for (int n = 0; n < 2; ++n){
      int col = g*512 + jb*32 + n*16 + llo;
      bias2[g][n] = bih[col] + bhh[col];
      wihv[g][n]  = Wih[col];
    }
#pragma unroll
  for (int n = 0; n < 2; ++n) v1v[n] = v1[jb*32 + n*16 + llo];

  for (int i = tid; i < 256*T_STEPS; i += 256)
    ys[i] = y[(size_t)b0*T_STEPS + i];

  // ---- W preload (once): 96 chunks, 24 per wave ----
#pragma unroll
  for (int i = 0; i < 24; ++i){
    int c = w*24 + i;                        // c = (g*2 + jt)*16 + kc
    int g = c >> 5, jt = (c >> 4) & 1, kc = c & 15;
    int J = jb*2 + jt;
    int ch = (((J >> 2)*4 + (J & 3))*4 + g)*16 + kc;
    gld_lds16(wpack + (size_t)ch*512 + lane*8, Wlds + c*512);
  }

  // ---- A source pointer & stage(0) ----
  const ushort_t* asrc = hbf + (size_t)tile*1310720 + (size_t)(w*64 + lane)*8;
  {
    ushort_t* dst = &Ab[0][w][0];
    gld_lds16(asrc,        dst);
    gld_lds16(asrc + 2048, dst + 512);
    gld_lds16(asrc + 4096, dst + 1024);
    gld_lds16(asrc + 6144, dst + 1536);
    asrc += 8192;
  }
  asm volatile("s_waitcnt vmcnt(0) lgkmcnt(0)" ::: "memory");
  __builtin_amdgcn_sched_barrier(0);
  __builtin_amdgcn_s_barrier();                // publish Wlds + ys

  f32x4 acc[4][3][2];
  f32x4 acco[4][2];
  float cst[4][2][4];
#pragma unroll
  for (int m = 0; m < 4; ++m)
#pragma unroll
    for (int n = 0; n < 2; ++n){
#pragma unroll
      for (int g = 0; g < 3; ++g) acc[m][g][n] = (f32x4){0.f,0.f,0.f,0.f};
      acco[m][n] = (f32x4){0.f,0.f,0.f,0.f};
#pragma unroll
      for (int r = 0; r < 4; ++r) cst[m][n][r] = 0.f;
    }

  RegSet sA, sB;
  const int aoff = (lhi*64 + llo)*8;           // + m*128 ushorts
  {
    const ushort_t* ar = &Ab[0][w][aoff];
#pragma unroll
    for (int m = 0; m < 4; ++m) sA.af[m] = *(const short8*)(ar + m*128);
#pragma unroll
    for (int g = 0; g < 3; ++g)
#pragma unroll
      for (int n = 0; n < 2; ++n)
        sA.wf[g][n] = *(const short8*)(Wlds + ((g*2+n)*16 + 0)*512 + lane*8);
  }

  auto body = [&](int ss, RegSet& cur, RegSet& nxt){
    int ns = ss + 1;
    if (ns < 176){                             // stage slice ns (own region)
      if (ns == 160) asrc -= 131072;           // t jumps to 9, kc back to 0
      ushort_t* dst = &Ab[ns & 1][w][0];
      gld_lds16(asrc,        dst);
      gld_lds16(asrc + 2048, dst + 512);
      gld_lds16(asrc + 4096, dst + 1024);
      gld_lds16(asrc + 6144, dst + 1536);
      asrc += 8192;
    }
    int kc = ss & 15;
    if (ss < 160){
#pragma unroll
      for (int g = 0; g < 3; ++g)
#pragma unroll
        for (int n = 0; n < 2; ++n)
#pragma unroll
          for (int m = 0; m < 4; ++m)
            acc[m][g][n] = __builtin_amdgcn_mfma_f32_16x16x32_bf16(
                cur.af[m], cur.wf[g][n], acc[m][g][n], 0, 0, 0);
      if (kc == 15){
        int t = ss >> 4;
#pragma unroll
        for (int m = 0; m < 4; ++m)
#pragma unroll
          for (int r = 0; r < 4; ++r){
            float yr = ys[(w*64 + m*16 + lhi*4 + r)*T_STEPS + t];
#pragma unroll
            for (int n = 0; n < 2; ++n){
              float pi = acc[m][0][n][r] + fmaf(yr, wihv[0][n], bias2[0][n]);
              float pf = acc[m][1][n][r] + fmaf(yr, wihv[1][n], bias2[1][n]);
              float pg = acc[m][2][n][r] + fmaf(yr, wihv[2][n], bias2[2][n]);
              cst[m][n][r] = sigf(pf)*cst[m][n][r] + sigf(pi)*tanh_(pg);
            }
          }
#pragma unroll
        for (int m = 0; m < 4; ++m)
#pragma unroll
          for (int g = 0; g < 3; ++g)
#pragma unroll
            for (int n = 0; n < 2; ++n) acc[m][g][n] = (f32x4){0.f,0.f,0.f,0.f};
      }
    } else {                                   // o-gate at t=9, W direct
      short8 wo[2];
#pragma unroll
      for (int n = 0; n < 2; ++n){
        int J = jb*2 + n;
        int ch = (((J >> 2)*4 + (J & 3))*4 + 3)*16 + kc;
        wo[n] = *(const short8*)(wpack + (size_t)ch*512 + lane*8);
      }
#pragma unroll
      for (int n = 0; n < 2; ++n)
#pragma unroll
        for (int m = 0; m < 4; ++m)
          acco[m][n] = __builtin_amdgcn_mfma_f32_16x16x32_bf16(
              cur.af[m], wo[n], acco[m][n], 0, 0, 0);
    }
    if (ns < 176){                             // own stage landed; read next set
      asm volatile("s_waitcnt vmcnt(0)" ::: "memory");
      __builtin_amdgcn_sched_barrier(0);
      const ushort_t* ar = &Ab[ns & 1][w][aoff];
#pragma unroll
      for (int m = 0; m < 4; ++m) nxt.af[m] = *(const short8*)(ar + m*128);
      if (ns < 160){
        int nkc = ns & 15;
#pragma unroll
        for (int g = 0; g < 3; ++g)
#pragma unroll
          for (int n = 0; n < 2; ++n)
            nxt.wf[g][n] = *(const short8*)(Wlds + ((g*2+n)*16 + nkc)*512 + lane*8);
      }
    }
  };

#pragma unroll 1
  for (int i = 0; i < 88; ++i){
    body(2*i,     sA, sB);
    body(2*i + 1, sB, sA);
  }

  // ---- epilogue: part = sig(o)*tanh(c)*v1, reduce over 16 j-lanes ----------
#pragma unroll
  for (int m = 0; m < 4; ++m)
#pragma unroll
    for (int r = 0; r < 4; ++r){
      float yr = ys[(w*64 + m*16 + lhi*4 + r)*T_STEPS + 9];
      float val = 0.f;
#pragma unroll
      for (int n = 0; n < 2; ++n){
        float po = acco[m][n][r] + fmaf(yr, wihv[3][n], bias2[3][n]);
        val += sigf(po)*tanh_(cst[m][n][r])*v1v[n];
      }
      val += __shfl_xor(val, 1);
      val += __shfl_xor(val, 2);
      val += __shfl_xor(val, 4);
      val += __shfl_xor(val, 8);
      if (llo == 0)
        atomicAdd(&out[b0 + w*64 + m*16 + lhi*4 + r], val);
    }
}

// ============================================================================
// K1 fallback (!PREP): R14 structure (passed) — A LDS-staged from fp32 h.
// ============================================================================
__global__ __launch_bounds__(256)
__attribute__((amdgpu_waves_per_eu(2, 2)))
void k_main_f(const float* __restrict__ h, const float* __restrict__ y,
              const float* __restrict__ Wih, const float* __restrict__ bih,
              const float* __restrict__ bhh,
              const ushort_t* __restrict__ wpack, const float* __restrict__ v1,
              float* __restrict__ out)
{
  __shared__ __align__(16) ushort_t Abf[2][4096];
  __shared__ float ysf[128*T_STEPS];

  int tid = threadIdx.x;
  int w = tid >> 6, lane = tid & 63, lhi = lane >> 4, llo = lane & 15;
  int mh = w & 1, wj = w >> 1;
  int bid = blockIdx.x;
  int xcd = bid & 7, q = bid >> 3;
  int jb = q >> 3, tile = xcd*8 + (q & 7);
  int b0 = tile * 128;

  float bias2[4][2], wihv[4][2], v1v[2];
#pragma unroll
  for (int g = 0; g < 4; ++g)
#pragma unroll
    for (int n = 0; n < 2; ++n){
      int col = g*512 + jb*64 + (wj*2+n)*16 + llo;
      bias2[g][n] = bih[col] + bhh[col];
      wihv[g][n]  = Wih[col];
    }
#pragma unroll
  for (int n = 0; n < 2; ++n) v1v[n] = v1[jb*64 + (wj*2+n)*16 + llo];

  for (int i = tid; i < 128*T_STEPS; i += 256)
    ysf[i] = y[(size_t)b0*T_STEPS + i];

  const ushort_t* wbase = wpack + (size_t)(jb*4 + wj*2)*32768 + lane*8;

  auto stageA_f = [&](int parity, int ss){
    int t = (ss < 160) ? (ss >> 4) : 9;
    int kc = ss & 15;
#pragma unroll
    for (int i = 0; i < 2; ++i){
      int gidx = tid + i*256;
      int kq = gidx >> 7, row = gidx & 127;
      const float* p = h + ((size_t)(b0+row)*T_STEPS + t)*512 + kc*32 + kq*8;
      float4 x0 = *(const float4*)p, x1 = *(const float4*)(p+4);
      uint4 pk;
      pk.x = pk2(x0.x,x0.y); pk.y = pk2(x0.z,x0.w);
      pk.z = pk2(x1.x,x1.y); pk.w = pk2(x1.z,x1.w);
      *(uint4*)&Abf[parity][gidx*8] = pk;
    }
  };

  stageA_f(0, 0);
  __syncthreads();

  f32x4 acc[4][3][2];
  float cst[4][2][4];
#pragma unroll
  for (int m = 0; m < 4; ++m)
#pragma unroll
    for (int n = 0; n < 2; ++n){
#pragma unroll
      for (int g = 0; g < 3; ++g) acc[m][g][n] = (f32x4){0.f,0.f,0.f,0.f};
#pragma unroll
      for (int r = 0; r < 4; ++r) cst[m][n][r] = 0.f;
    }

  const int aro = (lhi*128 + mh*64 + llo)*8;

#pragma unroll 1
  for (int s = 0; s < 160; ++s){
    if (s < 159) stageA_f((s+1)&1, s+1);
    else         stageA_f(0, 160);

    int kco = (s & 15) * 512;
    short8 wf[3][2];
#pragma unroll
    for (int g = 0; g < 3; ++g)
#pragma unroll
      for (int n = 0; n < 2; ++n)
        wf[g][n] = *(const short8*)(wbase + (size_t)(n*4+g)*8192 + kco);

    const ushort_t* ap = &Abf[s&1][aro];
    short8 af[4];
#pragma unroll
    for (int m = 0; m < 4; ++m)
      af[m] = *(const short8*)(ap + m*128);

#pragma unroll
    for (int g = 0; g < 3; ++g)
#pragma unroll
      for (int n = 0; n < 2; ++n)
#pragma unroll
        for (int m = 0; m < 4; ++m)
          acc[m][g][n] = __builtin_amdgcn_mfma_f32_16x16x32_bf16(
              af[m], wf[g][n], acc[m][g][n], 0, 0, 0);

    if ((s & 15) == 15){
      int t = s >> 4;
#pragma unroll
      for (int m = 0; m < 4; ++m)
#pragma unroll
        for (int r = 0; r < 4; ++r){
          float yr = ysf[(mh*64 + m*16 + lhi*4 + r)*T_STEPS + t];
#pragma unroll
          for (int n = 0; n < 2; ++n){
            float pi = acc[m][0][n][r] + fmaf(yr, wihv[0][n], bias2[0][n]);
            float pf = acc[m][1][n][r] + fmaf(yr, wihv[1][n], bias2[1][n]);
            float pg = acc[m][2][n][r] + fmaf(yr, wihv[2][n], bias2[2][n]);
            cst[m][n][r] = sigf(pf)*cst[m][n][r] + sigf(pi)*tanh_(pg);
          }
        }
#pragma unroll
      for (int m = 0; m < 4; ++m)
#pragma unroll
        for (int g = 0; g < 3; ++g)
#pragma unroll
          for (int n = 0; n < 2; ++n) acc[m][g][n] = (f32x4){0.f,0.f,0.f,0.f};
    }
    __syncthreads();
  }

  f32x4 acco[4][2];
#pragma unroll
  for (int m = 0; m < 4; ++m)
#pragma unroll
    for (int n = 0; n < 2; ++n) acco[m][n] = (f32x4){0.f,0.f,0.f,0.f};

#pragma unroll 1
  for (int s2 = 0; s2 < 16; ++s2){
    if (s2 < 15) stageA_f((s2+1)&1, 161+s2);
    int kco = s2 * 512;
    short8 wo[2];
#pragma unroll
    for (int n = 0; n < 2; ++n)
      wo[n] = *(const short8*)(wbase + (size_t)(n*4+3)*8192 + kco);

    const ushort_t* ap = &Abf[s2&1][aro];
    short8 af[4];
#pragma unroll
    for (int m = 0; m < 4; ++m)
      af[m] = *(const short8*)(ap + m*128);
#pragma unroll
    for (int n = 0; n < 2; ++n)
#pragma unroll
      for (int m = 0; m < 4; ++m)
        acco[m][n] = __builtin_amdgcn_mfma_f32_16x16x32_bf16(
            af[m], wo[n], acco[m][n], 0, 0, 0);
    __syncthreads();
  }

#pragma unroll
  for (int m = 0; m < 4; ++m)
#pragma unroll
    for (int r = 0; r < 4; ++r){
      float yr = ysf[(mh*64 + m*16 + lhi*4 + r)*T_STEPS + 9];
      float val = 0.f;
#pragma unroll
      for (int n = 0; n < 2; ++n){
        float po = acco[m][n][r] + fmaf(yr, wihv[3][n], bias2[3][n]);
        val += sigf(po)*tanh_(cst[m][n][r])*v1v[n];
      }
      val += __shfl_xor(val, 1);
      val += __shfl_xor(val, 2);
      val += __shfl_xor(val, 4);
      val += __shfl_xor(val, 8);
      if (llo == 0)
        atomicAdd(&out[b0 + mh*64 + m*16 + lhi*4 + r], val);
    }
}

extern "C" void kernel_launch(void* const* d_in, const int* in_sizes, int n_in,
                              void* d_out, int out_size, void* d_ws, size_t ws_size,
                              hipStream_t stream){
  (void)in_sizes; (void)n_in; (void)out_size;
  const float* h    = (const float*)d_in[0];
  const float* y    = (const float*)d_in[1];
  // d_in[2..7] = attention weights: mathematically dead (softmax over size-1 dim == 1)
  const float* Wih  = (const float*)d_in[8];
  const float* Whh  = (const float*)d_in[9];
  const float* bih  = (const float*)d_in[10];
  const float* bhh  = (const float*)d_in[11];
  const float* fc1w = (const float*)d_in[12];
  const float* fc1b = (const float*)d_in[13];
  const float* fc2w = (const float*)d_in[14];
  const float* fc2b = (const float*)d_in[15];
  float* out = (float*)d_out;

  ushort_t* wpack = (ushort_t*)d_ws;
  float* vbuf  = (float*)((char*)d_ws + VBUF_OFF);
  float* bias0 = vbuf + 1024;
  ushort_t* hbf = (ushort_t*)((char*)d_ws + HBF_OFF);
  bool prep = ws_size >= (size_t)HBF_OFF + HBF_BYTES;

  k_pack<<<512, 256, 0, stream>>>(Whh, wpack);
  k_v<<<17, 256, 0, stream>>>(fc1w, fc1b, fc2w, fc2b, vbuf, bias0);
  if (prep)
    k_prep<<<640, 256, 0, stream>>>(h, hbf);
  k_init<<<128, 512, 0, stream>>>(h, vbuf, bias0, out);
  if (prep)
    k_main_p<<<512, 256, 0, stream>>>(hbf, y, Wih, bih, bhh, wpack, vbuf, out);
  else
    k_main_f<<<512, 256, 0, stream>>>(h, y, Wih, bih, bhh, wpack, vbuf, out);
}

// Round 17
// 229.810 us; speedup vs baseline: 1.8281x; 1.8281x over previous
//
#include <hip/hip_runtime.h>
#include <stdint.h>

typedef __attribute__((ext_vector_type(8))) short short8;
typedef __attribute__((ext_vector_type(4))) float f32x4;
typedef unsigned short ushort_t;

#define T_STEPS 10
#define WPACK_BYTES (2048*1024)                 // 2048 chunks x 1 KiB
#define VBUF_OFF  WPACK_BYTES
#define HBF_OFF   (WPACK_BYTES + 8192)
#define H_ELEMS   (8192ull*T_STEPS*512)
#define HBF_BYTES (H_ELEMS*2)

typedef const __attribute__((address_space(1))) void gas_void;
typedef __attribute__((address_space(3))) void las_void;

__device__ __forceinline__ void gld_lds16(const void* g, void* l){
  __builtin_amdgcn_global_load_lds((gas_void*)g, (las_void*)l, 16, 0, 0);
}

__device__ __forceinline__ unsigned int pk2(float x, float y){
  unsigned int bx = __float_as_uint(x), by = __float_as_uint(y);
  bx = (bx + 0x7FFFu + ((bx>>16)&1u)) >> 16;     // RNE fp32->bf16
  by = (by + 0x7FFFu + ((by>>16)&1u)) >> 16;
  return bx | (by<<16);
}
__device__ __forceinline__ float sigf(float x){ return 1.f/(1.f + __expf(-x)); }
__device__ __forceinline__ float tanh_(float x){
  x = fminf(fmaxf(x, -15.f), 15.f);
  float e = __expf(2.f*x);
  return (e - 1.f)/(e + 1.f);
}

// ---- K0a: pack W_hh [2048][512] fp32 -> bf16 B-fragment chunks -------------
// chunk = ((jb4*4 + jt4)*4 + g)*16 + kc (jb4 0..7 block of 64 j, jt4 0..3)
__global__ __launch_bounds__(256) void k_pack(const float* __restrict__ Whh,
                                              ushort_t* __restrict__ wp){
  int id  = blockIdx.x*256 + threadIdx.x;
  int row = id >> 6;
  int ko  = (id & 63) * 8;
  const float* p = Whh + row*512 + ko;
  float4 a = *(const float4*)p, b = *(const float4*)(p+4);
  uint4 v;
  v.x = pk2(a.x,a.y); v.y = pk2(a.z,a.w);
  v.z = pk2(b.x,b.y); v.w = pk2(b.z,b.w);
  int g = row >> 9, j = row & 511;
  int jb = j >> 6, jt = (j >> 4) & 3, jl = j & 15;
  int kc = ko >> 5, khi = (ko >> 3) & 3, lane = khi*16 + jl;
  int chunk = ((jb*4 + jt)*4 + g)*16 + kc;
  *(uint4*)(wp + chunk*512 + lane*8) = v;
}

// ---- K0b -------------------------------------------------------------------
__global__ __launch_bounds__(256) void k_v(const float* __restrict__ fc1w,
                                           const float* __restrict__ fc1b,
                                           const float* __restrict__ fc2w,
                                           const float* __restrict__ fc2b,
                                           float* __restrict__ vout,
                                           float* __restrict__ bias0){
  __shared__ float red[4][64];
  int tid = threadIdx.x;
  if (blockIdx.x < 16){
    int j  = blockIdx.x*64 + (tid & 63);
    int hc = tid >> 6;
    float s = 0.f;
    for (int hh = hc*128; hh < hc*128 + 128; ++hh)
      s += fc2w[hh] * fc1w[hh*1024 + j];
    red[hc][tid & 63] = s;
    __syncthreads();
    if (tid < 64)
      vout[blockIdx.x*64 + tid] = red[0][tid]+red[1][tid]+red[2][tid]+red[3][tid];
  } else {
    if (tid < 64){
      float s = 0.f;
      for (int i = 0; i < 8; ++i){ int hh = i*64 + tid; s += fc2w[hh]*fc1b[hh]; }
      for (int m = 32; m; m >>= 1) s += __shfl_xor(s, m);
      if (tid == 0) *bias0 = s + fc2b[0];
    }
  }
}

// ---- K2 --------------------------------------------------------------------
__global__ __launch_bounds__(512) void k_init(const float* __restrict__ h,
                                              const float* __restrict__ v,
                                              const float* __restrict__ bias0,
                                              float* __restrict__ out){
  int w = threadIdx.x >> 6, lane = threadIdx.x & 63;
  float b0v = *bias0;
  const float* v2 = v + 512;
  for (int r = 0; r < 8; ++r){
    int b = blockIdx.x*64 + w*8 + r;
    const float* hp = h + ((size_t)b*T_STEPS + 9)*512 + lane*8;
    float4 x0 = *(const float4*)hp, x1 = *(const float4*)(hp+4);
    const float* vp = v2 + lane*8;
    float4 w0 = *(const float4*)vp, w1 = *(const float4*)(vp+4);
    float s = x0.x*w0.x + x0.y*w0.y + x0.z*w0.z + x0.w*w0.w
            + x1.x*w1.x + x1.y*w1.y + x1.z*w1.z + x1.w*w1.w;
    for (int m = 32; m; m >>= 1) s += __shfl_xor(s, m);
    if (lane == 0) out[b] = s + b0v;
  }
}

// ---- K0c: h fp32 -> bf16, quad-major per-slice, BT=256 tiles ---------------
// hbf granule(16B) = ((tile*10 + t)*16 + kc)*1024 + kq*256 + row
// grid = 32 tiles x 10 t x 2 row-halves = 640 blocks x 256 threads.
__global__ __launch_bounds__(256) void k_prep(const float* __restrict__ h,
                                              ushort_t* __restrict__ hbf){
  __shared__ __align__(16) ushort_t buf[8192*8];     // 128 KiB
  int bid = blockIdx.x;
  int T = bid / 20, rem = bid % 20, t = rem >> 1, half = rem & 1;
  int tid = threadIdx.x;
  int row128 = tid >> 1, khalf = tid & 1;
  const float* src = h + ((size_t)(T*256 + half*128 + row128)*T_STEPS + t)*512
                   + khalf*256;
#pragma unroll
  for (int g = 0; g < 32; ++g){
    int k0 = khalf*256 + g*8;
    float4 a = *(const float4*)(src + g*8);
    float4 b = *(const float4*)(src + g*8 + 4);
    uint4 pk;
    pk.x = pk2(a.x,a.y); pk.y = pk2(a.z,a.w);
    pk.z = pk2(b.x,b.y); pk.w = pk2(b.z,b.w);
    int kc = k0 >> 5, kq = (k0 >> 3) & 3;
    *(uint4*)&buf[(size_t)(kc*512 + kq*128 + row128)*8] = pk;
  }
  __syncthreads();
  size_t sb = ((size_t)(T*T_STEPS + t)*16)*1024;
#pragma unroll
  for (int i = 0; i < 32; ++i){
    int gr = tid + i*256;                        // buf granule (kc,kq,r)
    int kc = gr >> 9, kq = (gr >> 7) & 3, r = gr & 127;
    size_t dg = sb + (size_t)kc*1024 + kq*256 + half*128 + r;
    *(uint4*)(hbf + dg*8) = *(const uint4*)&buf[gr*8];
  }
}

// ============================================================================
// K1 (PREP): R14 loop idiom + W-in-LDS-once, 8 waves (2/SIMD).
// 512 blocks (32 tiles x 16 jb) x 512 thr. BT=256, Jb=32.
// Wave tile: m2 (32 rows) x n2 (32 j) x 3 gates = 12 MFMA/slice.
// W{i,f,g} (96 KB) in LDS once; A register-direct from hbf (no LDS/barriers);
// named A/B register sets, compiler-scheduled waits (R14-proven idiom).
// R16 BUG FIX: BT=256 slice = 8192 ushorts (not 4096) -> in-loop A strides
// are +8192 (set B), +16384 (next set A), ap += 16384 per 2-slice kp.
// ============================================================================
__global__ __launch_bounds__(512)
__attribute__((amdgpu_waves_per_eu(2, 2)))
void k_main_p(const ushort_t* __restrict__ hbf, const float* __restrict__ y,
              const float* __restrict__ Wih, const float* __restrict__ bih,
              const float* __restrict__ bhh,
              const ushort_t* __restrict__ wpack, const float* __restrict__ v1,
              float* __restrict__ out)
{
  __shared__ __align__(16) ushort_t Wlds[96*512];    // 96 KiB, read-only
  __shared__ float ys[256*T_STEPS];                  // 10 KiB

  int tid = threadIdx.x;
  int w = tid >> 6, lane = tid & 63, lhi = lane >> 4, llo = lane & 15;
  int bid = blockIdx.x;
  int xcd = bid & 7, q = bid >> 3;
  int jb  = q & 15;                                  // j-block of 32
  int tile = xcd*4 + (q >> 4);                       // 0..31; 16 jb-sibs same XCD
  int b0 = tile * 256;

  float bias2[4][2], wihv[4][2], v1v[2];
#pragma unroll
  for (int g = 0; g < 4; ++g)
#pragma unroll
    for (int n = 0; n < 2; ++n){
      int col = g*512 + jb*32 + n*16 + llo;
      bias2[g][n] = bih[col] + bhh[col];
      wihv[g][n]  = Wih[col];
    }
#pragma unroll
  for (int n = 0; n < 2; ++n) v1v[n] = v1[jb*32 + n*16 + llo];

  for (int i = tid; i < 256*T_STEPS; i += 512)
    ys[i] = y[(size_t)b0*T_STEPS + i];

  // ---- W preload (once): 96 chunks, 12 per wave ----
#pragma unroll
  for (int i = 0; i < 12; ++i){
    int c = w*12 + i;                        // c = (g*2 + n)*16 + kc
    int g = c >> 5, n = (c >> 4) & 1, kc = c & 15;
    int ch = (((jb >> 1)*4 + ((jb & 1)*2 + n))*4 + g)*16 + kc;
    gld_lds16(wpack + (size_t)ch*512 + lane*8, Wlds + c*512);
  }
  __syncthreads();                           // Wlds + ys published (one-time)

  const ushort_t* wl = Wlds + lane*8;
  const ushort_t* aT = hbf + (size_t)tile*1310720
                     + (size_t)(lhi*256 + w*32 + llo)*8;

  f32x4 acc[2][3][2];
  float cst[2][2][4];
#pragma unroll
  for (int m = 0; m < 2; ++m)
#pragma unroll
    for (int n = 0; n < 2; ++n){
#pragma unroll
      for (int g = 0; g < 3; ++g) acc[m][g][n] = (f32x4){0.f,0.f,0.f,0.f};
#pragma unroll
      for (int r = 0; r < 4; ++r) cst[m][n][r] = 0.f;
    }

#pragma unroll 1
  for (int t = 0; t < T_STEPS; ++t){
    const ushort_t* ap = aT;
    short8 afA[2], wfA[3][2], afB[2], wfB[3][2];
#pragma unroll
    for (int m = 0; m < 2; ++m) afA[m] = *(const short8*)(ap + m*128);
#pragma unroll
    for (int g = 0; g < 3; ++g)
#pragma unroll
      for (int n = 0; n < 2; ++n)
        wfA[g][n] = *(const short8*)(wl + (g*2+n)*8192);

#pragma unroll 1
    for (int kp = 0; kp < 8; ++kp){
      const ushort_t* wk1 = wl + (2*kp + 1)*512;
#pragma unroll
      for (int m = 0; m < 2; ++m) afB[m] = *(const short8*)(ap + 8192 + m*128);
#pragma unroll
      for (int g = 0; g < 3; ++g)
#pragma unroll
        for (int n = 0; n < 2; ++n)
          wfB[g][n] = *(const short8*)(wk1 + (g*2+n)*8192);
#pragma unroll
      for (int g = 0; g < 3; ++g)
#pragma unroll
        for (int n = 0; n < 2; ++n)
#pragma unroll
          for (int m = 0; m < 2; ++m)
            acc[m][g][n] = __builtin_amdgcn_mfma_f32_16x16x32_bf16(
                afA[m], wfA[g][n], acc[m][g][n], 0, 0, 0);
      if (kp < 7){
        const ushort_t* wk2 = wl + (2*kp + 2)*512;
#pragma unroll
        for (int m = 0; m < 2; ++m) afA[m] = *(const short8*)(ap + 16384 + m*128);
#pragma unroll
        for (int g = 0; g < 3; ++g)
#pragma unroll
          for (int n = 0; n < 2; ++n)
            wfA[g][n] = *(const short8*)(wk2 + (g*2+n)*8192);
      }
#pragma unroll
      for (int g = 0; g < 3; ++g)
#pragma unroll
        for (int n = 0; n < 2; ++n)
#pragma unroll
          for (int m = 0; m < 2; ++m)
            acc[m][g][n] = __builtin_amdgcn_mfma_f32_16x16x32_bf16(
                afB[m], wfB[g][n], acc[m][g][n], 0, 0, 0);
      ap += 16384;
    }

    // cell update
#pragma unroll
    for (int m = 0; m < 2; ++m)
#pragma unroll
      for (int r = 0; r < 4; ++r){
        float yr = ys[(w*32 + m*16 + lhi*4 + r)*T_STEPS + t];
#pragma unroll
        for (int n = 0; n < 2; ++n){
          float pi = acc[m][0][n][r] + fmaf(yr, wihv[0][n], bias2[0][n]);
          float pf = acc[m][1][n][r] + fmaf(yr, wihv[1][n], bias2[1][n]);
          float pg = acc[m][2][n][r] + fmaf(yr, wihv[2][n], bias2[2][n]);
          cst[m][n][r] = sigf(pf)*cst[m][n][r] + sigf(pi)*tanh_(pg);
        }
      }
#pragma unroll
    for (int m = 0; m < 2; ++m)
#pragma unroll
      for (int g = 0; g < 3; ++g)
#pragma unroll
        for (int n = 0; n < 2; ++n) acc[m][g][n] = (f32x4){0.f,0.f,0.f,0.f};

    aT += 131072;
  }

  // ---- o-gate sweep at t=9 (register-direct W_o, same dbuf idiom) ---------
  f32x4 acco[2][2];
#pragma unroll
  for (int m = 0; m < 2; ++m)
#pragma unroll
    for (int n = 0; n < 2; ++n) acco[m][n] = (f32x4){0.f,0.f,0.f,0.f};

  {
    const ushort_t* ap = aT - 131072;        // t = 9
    const ushort_t* wo0 = wpack + (size_t)((((jb>>1)*4 + (jb&1)*2 + 0)*4 + 3)*16)*512 + lane*8;
    const ushort_t* wo1 = wpack + (size_t)((((jb>>1)*4 + (jb&1)*2 + 1)*4 + 3)*16)*512 + lane*8;
    short8 afA[2], woA[2], afB[2], woB[2];
#pragma unroll
    for (int m = 0; m < 2; ++m) afA[m] = *(const short8*)(ap + m*128);
    woA[0] = *(const short8*)(wo0);
    woA[1] = *(const short8*)(wo1);

#pragma unroll 1
    for (int kp = 0; kp < 8; ++kp){
#pragma unroll
      for (int m = 0; m < 2; ++m) afB[m] = *(const short8*)(ap + 8192 + m*128);
      woB[0] = *(const short8*)(wo0 + (2*kp+1)*512);
      woB[1] = *(const short8*)(wo1 + (2*kp+1)*512);
#pragma unroll
      for (int n = 0; n < 2; ++n)
#pragma unroll
        for (int m = 0; m < 2; ++m)
          acco[m][n] = __builtin_amdgcn_mfma_f32_16x16x32_bf16(
              afA[m], woA[n], acco[m][n], 0, 0, 0);
      if (kp < 7){
#pragma unroll
        for (int m = 0; m < 2; ++m) afA[m] = *(const short8*)(ap + 16384 + m*128);
        woA[0] = *(const short8*)(wo0 + (2*kp+2)*512);
        woA[1] = *(const short8*)(wo1 + (2*kp+2)*512);
      }
#pragma unroll
      for (int n = 0; n < 2; ++n)
#pragma unroll
        for (int m = 0; m < 2; ++m)
          acco[m][n] = __builtin_amdgcn_mfma_f32_16x16x32_bf16(
              afB[m], woB[n], acco[m][n], 0, 0, 0);
      ap += 16384;
    }
  }

  // ---- epilogue: part = sig(o)*tanh(c)*v1, reduce over 16 j-lanes ----------
#pragma unroll
  for (int m = 0; m < 2; ++m)
#pragma unroll
    for (int r = 0; r < 4; ++r){
      float yr = ys[(w*32 + m*16 + lhi*4 + r)*T_STEPS + 9];
      float val = 0.f;
#pragma unroll
      for (int n = 0; n < 2; ++n){
        float po = acco[m][n][r] + fmaf(yr, wihv[3][n], bias2[3][n]);
        val += sigf(po)*tanh_(cst[m][n][r])*v1v[n];
      }
      val += __shfl_xor(val, 1);
      val += __shfl_xor(val, 2);
      val += __shfl_xor(val, 4);
      val += __shfl_xor(val, 8);
      if (llo == 0)
        atomicAdd(&out[b0 + w*32 + m*16 + lhi*4 + r], val);
    }
}

// ============================================================================
// K1 fallback (!PREP): R14 structure (proven) — A LDS-staged from fp32 h.
// ============================================================================
__global__ __launch_bounds__(256)
__attribute__((amdgpu_waves_per_eu(2, 2)))
void k_main_f(const float* __restrict__ h, const float* __restrict__ y,
              const float* __restrict__ Wih, const float* __restrict__ bih,
              const float* __restrict__ bhh,
              const ushort_t* __restrict__ wpack, const float* __restrict__ v1,
              float* __restrict__ out)
{
  __shared__ __align__(16) ushort_t Abf[2][4096];
  __shared__ float ysf[128*T_STEPS];

  int tid = threadIdx.x;
  int w = tid >> 6, lane = tid & 63, lhi = lane >> 4, llo = lane & 15;
  int mh = w & 1, wj = w >> 1;
  int bid = blockIdx.x;
  int xcd = bid & 7, q = bid >> 3;
  int jb = q >> 3, tile = xcd*8 + (q & 7);
  int b0 = tile * 128;

  float bias2[4][2], wihv[4][2], v1v[2];
#pragma unroll
  for (int g = 0; g < 4; ++g)
#pragma unroll
    for (int n = 0; n < 2; ++n){
      int col = g*512 + jb*64 + (wj*2+n)*16 + llo;
      bias2[g][n] = bih[col] + bhh[col];
      wihv[g][n]  = Wih[col];
    }
#pragma unroll
  for (int n = 0; n < 2; ++n) v1v[n] = v1[jb*64 + (wj*2+n)*16 + llo];

  for (int i = tid; i < 128*T_STEPS; i += 256)
    ysf[i] = y[(size_t)b0*T_STEPS + i];

  const ushort_t* wbase = wpack + (size_t)(jb*4 + wj*2)*32768 + lane*8;

  auto stageA_f = [&](int parity, int ss){
    int t = (ss < 160) ? (ss >> 4) : 9;
    int kc = ss & 15;
#pragma unroll
    for (int i = 0; i < 2; ++i){
      int gidx = tid + i*256;
      int kq = gidx >> 7, row = gidx & 127;
      const float* p = h + ((size_t)(b0+row)*T_STEPS + t)*512 + kc*32 + kq*8;
      float4 x0 = *(const float4*)p, x1 = *(const float4*)(p+4);
      uint4 pk;
      pk.x = pk2(x0.x,x0.y); pk.y = pk2(x0.z,x0.w);
      pk.z = pk2(x1.x,x1.y); pk.w = pk2(x1.z,x1.w);
      *(uint4*)&Abf[parity][gidx*8] = pk;
    }
  };

  stageA_f(0, 0);
  __syncthreads();

  f32x4 acc[4][3][2];
  float cst[4][2][4];
#pragma unroll
  for (int m = 0; m < 4; ++m)
#pragma unroll
    for (int n = 0; n < 2; ++n){
#pragma unroll
      for (int g = 0; g < 3; ++g) acc[m][g][n] = (f32x4){0.f,0.f,0.f,0.f};
#pragma unroll
      for (int r = 0; r < 4; ++r) cst[m][n][r] = 0.f;
    }

  const int aro = (lhi*128 + mh*64 + llo)*8;

#pragma unroll 1
  for (int s = 0; s < 160; ++s){
    if (s < 159) stageA_f((s+1)&1, s+1);
    else         stageA_f(0, 160);

    int kco = (s & 15) * 512;
    short8 wf[3][2];
#pragma unroll
    for (int g = 0; g < 3; ++g)
#pragma unroll
      for (int n = 0; n < 2; ++n)
        wf[g][n] = *(const short8*)(wbase + (size_t)(n*4+g)*8192 + kco);

    const ushort_t* ap = &Abf[s&1][aro];
    short8 af[4];
#pragma unroll
    for (int m = 0; m < 4; ++m)
      af[m] = *(const short8*)(ap + m*128);

#pragma unroll
    for (int g = 0; g < 3; ++g)
#pragma unroll
      for (int n = 0; n < 2; ++n)
#pragma unroll
        for (int m = 0; m < 4; ++m)
          acc[m][g][n] = __builtin_amdgcn_mfma_f32_16x16x32_bf16(
              af[m], wf[g][n], acc[m][g][n], 0, 0, 0);

    if ((s & 15) == 15){
      int t = s >> 4;
#pragma unroll
      for (int m = 0; m < 4; ++m)
#pragma unroll
        for (int r = 0; r < 4; ++r){
          float yr = ysf[(mh*64 + m*16 + lhi*4 + r)*T_STEPS + t];
#pragma unroll
          for (int n = 0; n < 2; ++n){
            float pi = acc[m][0][n][r] + fmaf(yr, wihv[0][n], bias2[0][n]);
            float pf = acc[m][1][n][r] + fmaf(yr, wihv[1][n], bias2[1][n]);
            float pg = acc[m][2][n][r] + fmaf(yr, wihv[2][n], bias2[2][n]);
            cst[m][n][r] = sigf(pf)*cst[m][n][r] + sigf(pi)*tanh_(pg);
          }
        }
#pragma unroll
      for (int m = 0; m < 4; ++m)
#pragma unroll
        for (int g = 0; g < 3; ++g)
#pragma unroll
          for (int n = 0; n < 2; ++n) acc[m][g][n] = (f32x4){0.f,0.f,0.f,0.f};
    }
    __syncthreads();
  }

  f32x4 acco[4][2];
#pragma unroll
  for (int m = 0; m < 4; ++m)
#pragma unroll
    for (int n = 0; n < 2; ++n) acco[m][n] = (f32x4){0.f,0.f,0.f,0.f};

#pragma unroll 1
  for (int s2 = 0; s2 < 16; ++s2){
    if (s2 < 15) stageA_f((s2+1)&1, 161+s2);
    int kco = s2 * 512;
    short8 wo[2];
#pragma unroll
    for (int n = 0; n < 2; ++n)
      wo[n] = *(const short8*)(wbase + (size_t)(n*4+3)*8192 + kco);

    const ushort_t* ap = &Abf[s2&1][aro];
    short8 af[4];
#pragma unroll
    for (int m = 0; m < 4; ++m)
      af[m] = *(const short8*)(ap + m*128);
#pragma unroll
    for (int n = 0; n < 2; ++n)
#pragma unroll
      for (int m = 0; m < 4; ++m)
        acco[m][n] = __builtin_amdgcn_mfma_f32_16x16x32_bf16(
            af[m], wo[n], acco[m][n], 0, 0, 0);
    __syncthreads();
  }

#pragma unroll
  for (int m = 0; m < 4; ++m)
#pragma unroll
    for (int r = 0; r < 4; ++r){
      float yr = ysf[(mh*64 + m*16 + lhi*4 + r)*T_STEPS + 9];
      float val = 0.f;
#pragma unroll
      for (int n = 0; n < 2; ++n){
        float po = acco[m][n][r] + fmaf(yr, wihv[3][n], bias2[3][n]);
        val += sigf(po)*tanh_(cst[m][n][r])*v1v[n];
      }
      val += __shfl_xor(val, 1);
      val += __shfl_xor(val, 2);
      val += __shfl_xor(val, 4);
      val += __shfl_xor(val, 8);
      if (llo == 0)
        atomicAdd(&out[b0 + mh*64 + m*16 + lhi*4 + r], val);
    }
}

extern "C" void kernel_launch(void* const* d_in, const int* in_sizes, int n_in,
                              void* d_out, int out_size, void* d_ws, size_t ws_size,
                              hipStream_t stream){
  (void)in_sizes; (void)n_in; (void)out_size;
  const float* h    = (const float*)d_in[0];
  const float* y    = (const float*)d_in[1];
  // d_in[2..7] = attention weights: mathematically dead (softmax over size-1 dim == 1)
  const float* Wih  = (const float*)d_in[8];
  const float* Whh  = (const float*)d_in[9];
  const float* bih  = (const float*)d_in[10];
  const float* bhh  = (const float*)d_in[11];
  const float* fc1w = (const float*)d_in[12];
  const float* fc1b = (const float*)d_in[13];
  const float* fc2w = (const float*)d_in[14];
  const float* fc2b = (const float*)d_in[15];
  float* out = (float*)d_out;

  ushort_t* wpack = (ushort_t*)d_ws;
  float* vbuf  = (float*)((char*)d_ws + VBUF_OFF);
  float* bias0 = vbuf + 1024;
  ushort_t* hbf = (ushort_t*)((char*)d_ws + HBF_OFF);
  bool prep = ws_size >= (size_t)HBF_OFF + HBF_BYTES;

  k_pack<<<512, 256, 0, stream>>>(Whh, wpack);
  k_v<<<17, 256, 0, stream>>>(fc1w, fc1b, fc2w, fc2b, vbuf, bias0);
  if (prep)
    k_prep<<<640, 256, 0, stream>>>(h, hbf);
  k_init<<<128, 512, 0, stream>>>(h, vbuf, bias0, out);
  if (prep)
    k_main_p<<<512, 512, 0, stream>>>(hbf, y, Wih, bih, bhh, wpack, vbuf, out);
  else
    k_main_f<<<512, 256, 0, stream>>>(h, y, Wih, bih, bhh, wpack, vbuf, out);
}